// Round 2
// baseline (294.695 us; speedup 1.0000x reference)
//
#include <hip/hip_runtime.h>
#include <stdint.h>

#define N_ROWS 8192
#define D_DIM  1024   // elements == bytes in fp8

typedef __attribute__((ext_vector_type(8)))  int   i32x8;
typedef __attribute__((ext_vector_type(4)))  int   i32x4;
typedef __attribute__((ext_vector_type(16))) float f32x16;

#define GLD16(gptr, lptr) __builtin_amdgcn_global_load_lds( \
    (const __attribute__((address_space(1))) void*)(gptr),  \
    (__attribute__((address_space(3))) void*)(lptr), 16, 0, 0)

// fp32 -> fp8 e4m3 convert. img scaled by 4*logit_scale, txt by 64.
// product carries 256*logit_scale -> epilogue divides acc by 256.
__global__ void convert_kernel(const float* __restrict__ img,
                               const float* __restrict__ txt,
                               const float* __restrict__ scale_p,
                               char* __restrict__ imgq, char* __restrict__ txtq) {
    const int  b      = blockIdx.x;
    const bool is_img = b < 2048;
    const float f     = is_img ? scale_p[0] * 4.0f : 64.0f;
    const float* src  = is_img ? img : txt;
    char* dst         = is_img ? imgq : txtq;
    const size_t idx  = ((size_t)(is_img ? b : b - 2048) * 256 + threadIdx.x) * 16;

    float4 x0 = *(const float4*)(src + idx);
    float4 x1 = *(const float4*)(src + idx + 4);
    float4 x2 = *(const float4*)(src + idx + 8);
    float4 x3 = *(const float4*)(src + idx + 12);
    int p0 = __builtin_amdgcn_cvt_pk_fp8_f32(x0.x * f, x0.y * f, 0, false);
    p0     = __builtin_amdgcn_cvt_pk_fp8_f32(x0.z * f, x0.w * f, p0, true);
    int p1 = __builtin_amdgcn_cvt_pk_fp8_f32(x1.x * f, x1.y * f, 0, false);
    p1     = __builtin_amdgcn_cvt_pk_fp8_f32(x1.z * f, x1.w * f, p1, true);
    int p2 = __builtin_amdgcn_cvt_pk_fp8_f32(x2.x * f, x2.y * f, 0, false);
    p2     = __builtin_amdgcn_cvt_pk_fp8_f32(x2.z * f, x2.w * f, p2, true);
    int p3 = __builtin_amdgcn_cvt_pk_fp8_f32(x3.x * f, x3.y * f, 0, false);
    p3     = __builtin_amdgcn_cvt_pk_fp8_f32(x3.z * f, x3.w * f, p3, true);
    *(i32x4*)(dst + idx) = (i32x4){p0, p1, p2, p3};
}

// 128x128 tile fp8 GEMM via mfma_scale_f32_32x32x64_f8f6f4 (unit scales).
// Epilogue: diag extraction (diagonal blocks), exp2, row/col sum atomics.
__global__ void __launch_bounds__(256, 3) gemm_exp_kernel(
        const char* __restrict__ A, const char* __restrict__ B,
        float* __restrict__ row_sum, float* __restrict__ col_sum,
        float* __restrict__ diag) {
    __shared__ __align__(16) char As[128 * 128];
    __shared__ __align__(16) char Bs[128 * 128];

    const int tid  = threadIdx.x;
    const int lane = tid & 63;
    const int w    = tid >> 6;      // wave 0..3
    const int wr   = w >> 1;
    const int wc   = w & 1;
    const int ti   = blockIdx.y * 128;
    const int tj   = blockIdx.x * 128;
    const int l31  = lane & 31;
    const int h    = lane >> 5;     // K-half selector for MFMA operands

    // staging: 64 lanes x 16B = 8 rows x 128B per GLD16; XOR-swizzled chunks
    const int srow8 = lane >> 3;              // 0..7
    const int sg    = (lane & 7) ^ srow8;     // global 16B chunk index

    f32x16 acc[2][2];
#pragma unroll
    for (int tr = 0; tr < 2; tr++)
#pragma unroll
        for (int tc = 0; tc < 2; tc++)
#pragma unroll
            for (int i = 0; i < 16; i++) acc[tr][tc][i] = 0.f;

    for (int k0 = 0; k0 < D_DIM; k0 += 128) {
#pragma unroll
        for (int c = 0; c < 4; c++) {
            const int ch = w * 4 + c;             // 0..15, wave-uniform
            const int r  = ch * 8 + srow8;        // tile row 0..127
            GLD16(A + (size_t)(ti + r) * D_DIM + k0 + sg * 16, As + ch * 1024);
            GLD16(B + (size_t)(tj + r) * D_DIM + k0 + sg * 16, Bs + ch * 1024);
        }
        __syncthreads();
#pragma unroll
        for (int ks = 0; ks < 2; ks++) {
            const int cb = ks * 4 + h * 2;        // 16B-chunk base for this lane's K-half
            i32x8 af[2], bfr[2];
#pragma unroll
            for (int tr = 0; tr < 2; tr++) {
                const int r = wr * 64 + tr * 32 + l31;
                const char* base = As + r * 128;
                const int p0 = ((cb ^ (r & 7)) << 4);
                i32x4 lo = *(const i32x4*)(base + p0);
                i32x4 hi = *(const i32x4*)(base + (p0 ^ 16));
                af[tr] = (i32x8){lo.x, lo.y, lo.z, lo.w, hi.x, hi.y, hi.z, hi.w};
            }
#pragma unroll
            for (int tc = 0; tc < 2; tc++) {
                const int r = wc * 64 + tc * 32 + l31;
                const char* base = Bs + r * 128;
                const int p0 = ((cb ^ (r & 7)) << 4);
                i32x4 lo = *(const i32x4*)(base + p0);
                i32x4 hi = *(const i32x4*)(base + (p0 ^ 16));
                bfr[tc] = (i32x8){lo.x, lo.y, lo.z, lo.w, hi.x, hi.y, hi.z, hi.w};
            }
#pragma unroll
            for (int tr = 0; tr < 2; tr++)
#pragma unroll
                for (int tc = 0; tc < 2; tc++)
                    acc[tr][tc] = __builtin_amdgcn_mfma_scale_f32_32x32x64_f8f6f4(
                        af[tr], bfr[tc], acc[tr][tc], 0, 0, 0, 127, 0, 127);
        }
        __syncthreads();
    }

    // ---- epilogue ----
    // C layout (32x32, verified): col = l31, row = (reg&3) + 8*(reg>>2) + 4*h
    const float INV256 = 1.0f / 256.0f;
    const float C_EXP  = 1.44269504088896340736f / 256.0f;

    // diag: raw logits on diagonal tiles (before exp)
    if (blockIdx.x == blockIdx.y && wr == wc) {
#pragma unroll
        for (int tr = 0; tr < 2; tr++) {
#pragma unroll
            for (int reg = 0; reg < 16; reg++) {
                const int row = (reg & 3) + 8 * (reg >> 2) + 4 * h;
                if (row == l31)
                    diag[ti + wr * 64 + tr * 32 + l31] = acc[tr][tr][reg] * INV256;
            }
        }
    }

#pragma unroll
    for (int tr = 0; tr < 2; tr++)
#pragma unroll
        for (int tc = 0; tc < 2; tc++)
#pragma unroll
            for (int reg = 0; reg < 16; reg++)
                acc[tr][tc][reg] = __builtin_amdgcn_exp2f(acc[tr][tc][reg] * C_EXP);

    // row sums: same row for all 32 lanes of a half at fixed (tr, reg)
#pragma unroll
    for (int tr = 0; tr < 2; tr++) {
#pragma unroll
        for (int reg = 0; reg < 16; reg++) {
            float s = acc[tr][0][reg] + acc[tr][1][reg];
            s += __shfl_xor(s, 1);
            s += __shfl_xor(s, 2);
            s += __shfl_xor(s, 4);
            s += __shfl_xor(s, 8);
            s += __shfl_xor(s, 16);
            if (l31 == 0)
                atomicAdd(&row_sum[ti + wr * 64 + tr * 32 +
                                   (reg & 3) + 8 * (reg >> 2) + 4 * h], s);
        }
    }

    // col sums: col = l31 for every reg; combine halves with xor 32
#pragma unroll
    for (int tc = 0; tc < 2; tc++) {
        float s = 0.f;
#pragma unroll
        for (int tr = 0; tr < 2; tr++)
#pragma unroll
            for (int reg = 0; reg < 16; reg++) s += acc[tr][tc][reg];
        s += __shfl_xor(s, 32);
        if (h == 0)
            atomicAdd(&col_sum[tj + wc * 64 + tc * 32 + l31], s);
    }
}

__global__ void finish_kernel(const float* __restrict__ rs, const float* __restrict__ cs,
                              const float* __restrict__ dg, float* __restrict__ out) {
    const int tid = threadIdx.x;   // 1024 threads
    float s = 0.f;
#pragma unroll
    for (int base = 0; base < N_ROWS; base += 4096) {
        float4 r = *(const float4*)(rs + base + tid * 4);
        float4 c = *(const float4*)(cs + base + tid * 4);
        float4 d = *(const float4*)(dg + base + tid * 4);
        s += __logf(r.x) + __logf(r.y) + __logf(r.z) + __logf(r.w);
        s += __logf(c.x) + __logf(c.y) + __logf(c.z) + __logf(c.w);
        s -= 2.f * (d.x + d.y + d.z + d.w);
    }
#pragma unroll
    for (int m = 1; m < 64; m <<= 1) s += __shfl_xor(s, m);
    __shared__ float wsum[16];
    if ((tid & 63) == 0) wsum[tid >> 6] = s;
    __syncthreads();
    if (tid == 0) {
        float t = 0.f;
#pragma unroll
        for (int i = 0; i < 16; i++) t += wsum[i];
        out[0] = t * (0.5f / (float)N_ROWS);
    }
}

extern "C" void kernel_launch(void* const* d_in, const int* in_sizes, int n_in,
                              void* d_out, int out_size, void* d_ws, size_t ws_size,
                              hipStream_t stream) {
    const float* img     = (const float*)d_in[0];
    const float* txt     = (const float*)d_in[1];
    const float* scale_p = (const float*)d_in[2];
    float* out = (float*)d_out;

    char* ws = (char*)d_ws;
    char*  imgq    = ws;                                          // 8 MB
    char*  txtq    = ws + (size_t)8 * 1024 * 1024;                // 8 MB
    float* row_sum = (float*)(ws + (size_t)16 * 1024 * 1024);     // 32 KB
    float* col_sum = row_sum + N_ROWS;                            // 32 KB
    float* diag    = col_sum + N_ROWS;                            // 32 KB

    hipMemsetAsync(row_sum, 0, 2 * N_ROWS * sizeof(float), stream);

    convert_kernel<<<4096, 256, 0, stream>>>(img, txt, scale_p, imgq, txtq);

    dim3 grid(N_ROWS / 128, N_ROWS / 128);
    gemm_exp_kernel<<<grid, 256, 0, stream>>>(imgq, txtq, row_sum, col_sum, diag);

    finish_kernel<<<1, 1024, 0, stream>>>(row_sum, col_sum, diag, out);
}